// Round 1
// baseline (603.420 us; speedup 1.0000x reference)
//
#include <hip/hip_runtime.h>
#include <stdint.h>

#define V_ 50257
#define D_ 1024
#define F_ 2048
#define B_ 64
#define E_ 512
#define ROWS_ (B_*E_)

// ---------------- ent_sum: masked row-sum over entity_hiddens ----------------
// mask dtype is ambiguous (bool bytes / int32 / float32). Detect from byte
// patterns: reading the first 32768 bytes is safe in all layouts.
//  - any uint with a nonzero byte above byte0 (and != 1.0f pattern) -> bool bytes
//  - else any uint == 0x3F800000 -> float32
//  - else -> int32
__global__ void k_ent_partial(const float* __restrict__ eh, const void* __restrict__ mask,
                              float* __restrict__ part) {
  __shared__ int s_mode;
  const int tid = threadIdx.x;
  const uint32_t* mu = (const uint32_t*)mask;
  int f = 0;
  for (int i = tid; i < (ROWS_ / 4); i += 256) {
    uint32_t u = mu[i];
    if (u == 0x3F800000u) f |= 2;
    else if (u & 0xFFFFFF00u) f |= 1;
  }
  if (tid == 0) s_mode = 0;
  __syncthreads();
  if (f) atomicOr(&s_mode, f);
  __syncthreads();
  const int sm = s_mode;
  const int mode = (sm & 1) ? 1 : ((sm & 2) ? 2 : 0);

  float4 acc = make_float4(0.f, 0.f, 0.f, 0.f);
  const float4* eh4 = (const float4*)eh;
  for (int row = blockIdx.x; row < ROWS_; row += gridDim.x) {
    bool on;
    if (mode == 1)      on = ((const unsigned char*)mask)[row] != 0;
    else if (mode == 2) on = ((const float*)mask)[row] != 0.f;
    else                on = ((const int*)mask)[row] != 0;
    if (on) {
      float4 v = eh4[(size_t)row * (D_ / 4) + tid];
      acc.x += v.x; acc.y += v.y; acc.z += v.z; acc.w += v.w;
    }
  }
  ((float4*)part)[(size_t)blockIdx.x * (D_ / 4) + tid] = acc;
}

__global__ void k_ent_reduce(const float* __restrict__ part, float* __restrict__ entsum) {
  int d = blockIdx.x * 256 + threadIdx.x;  // 4 blocks x 256 = 1024
  float s0 = 0.f, s1 = 0.f, s2 = 0.f, s3 = 0.f;
  for (int i = 0; i < 512; i += 4) {
    s0 += part[(size_t)(i    ) * D_ + d];
    s1 += part[(size_t)(i + 1) * D_ + d];
    s2 += part[(size_t)(i + 2) * D_ + d];
    s3 += part[(size_t)(i + 3) * D_ + d];
  }
  entsum[d] = (s0 + s1) + (s2 + s3);
}

// ---------------- small GEMM (M=64), split-K, writes partials ----------------
// block: 256 threads = 64 cols x 4 row-groups(16 rows). grid: (N/64, K/KB).
// X reads are wave-uniform (broadcast); W reads are lane-coalesced.
__global__ void k_gemm64(const float* __restrict__ X, const int* __restrict__ gatherIdx,
                         const float* __restrict__ emb, const float* __restrict__ W,
                         int K, int N, int KB, float* __restrict__ part) {
  const int l  = threadIdx.x & 63;
  const int rg = __builtin_amdgcn_readfirstlane((int)(threadIdx.x >> 6));
  const int c  = blockIdx.x * 64 + l;
  const int k0 = blockIdx.y * KB;
  const int m0 = rg * 16;

  const float* Xp = gatherIdx ? emb : X;
  int rb[16];
#pragma unroll
  for (int r = 0; r < 16; ++r) {
    int m = m0 + r;
    rb[r] = gatherIdx ? gatherIdx[m] * K : m * K;
  }

  float acc[16];
#pragma unroll
  for (int r = 0; r < 16; ++r) acc[r] = 0.f;

  for (int k = k0; k < k0 + KB; k += 4) {
    float w0 = W[(size_t)(k    ) * N + c];
    float w1 = W[(size_t)(k + 1) * N + c];
    float w2 = W[(size_t)(k + 2) * N + c];
    float w3 = W[(size_t)(k + 3) * N + c];
#pragma unroll
    for (int r = 0; r < 16; ++r) {
      float4 xv = *(const float4*)&Xp[rb[r] + k];
      acc[r] = fmaf(xv.x, w0, acc[r]);
      acc[r] = fmaf(xv.y, w1, acc[r]);
      acc[r] = fmaf(xv.z, w2, acc[r]);
      acc[r] = fmaf(xv.w, w3, acc[r]);
    }
  }
  size_t base = (size_t)blockIdx.y * ((size_t)64 * N);
#pragma unroll
  for (int r = 0; r < 16; ++r) part[base + (size_t)(m0 + r) * N + c] = acc[r];
}

// reduce split-K partials + epilogue.
// mode 1: relu(x + vecB[c]); 2: x + vecB[c]; 3: x * vecB[c]; 4: x + addend[idx]
__global__ void k_reduce_ep(const float* __restrict__ part, int nsplit, int MN, int N,
                            const float* __restrict__ vecB, const float* __restrict__ addend,
                            int mode, float* __restrict__ dst) {
  int idx = blockIdx.x * 256 + threadIdx.x;
  if (idx >= MN) return;
  float s = 0.f;
  for (int i = 0; i < nsplit; ++i) s += part[(size_t)i * MN + idx];
  int c = idx & (N - 1);  // N is a power of two
  if (mode == 1)      { s += vecB[c]; s = s > 0.f ? s : 0.f; }
  else if (mode == 2) { s += vecB[c]; }
  else if (mode == 3) { s *= vecB[c]; }
  else                { s += addend[idx]; }
  dst[idx] = s;
}

// ---------------- big GEMM: logits = Z[64,1024] @ Ws[1024,V] + bs ----------------
// block: 256 threads = 64 lane-pairs x 4 row-groups; 128 cols/block, 2 cols/thread.
// Z reads wave-uniform float4; Ws reads scalar (V odd -> float2 would misalign).
__global__ void k_gemm_big(const float* __restrict__ Z, const float* __restrict__ Ws,
                           const float* __restrict__ bs, float* __restrict__ logits) {
  const int l  = threadIdx.x & 63;
  const int rg = __builtin_amdgcn_readfirstlane((int)(threadIdx.x >> 6));
  const int c0 = blockIdx.x * 128 + 2 * l;
  const int m0 = rg * 16;
  const bool full = (blockIdx.x * 128 + 128) <= V_;

  float acc0[16], acc1[16];
#pragma unroll
  for (int r = 0; r < 16; ++r) { acc0[r] = 0.f; acc1[r] = 0.f; }

  if (full) {
    for (int k = 0; k < D_; k += 4) {
      const float* wp = Ws + (size_t)k * V_ + c0;
      float w0x = wp[0],        w0y = wp[1];
      float w1x = wp[V_],       w1y = wp[V_ + 1];
      float w2x = wp[2 * V_],   w2y = wp[2 * V_ + 1];
      float w3x = wp[3 * V_],   w3y = wp[3 * V_ + 1];
#pragma unroll
      for (int r = 0; r < 16; ++r) {
        float4 xv = *(const float4*)&Z[(m0 + r) * D_ + k];
        acc0[r] = fmaf(xv.x, w0x, acc0[r]);  acc1[r] = fmaf(xv.x, w0y, acc1[r]);
        acc0[r] = fmaf(xv.y, w1x, acc0[r]);  acc1[r] = fmaf(xv.y, w1y, acc1[r]);
        acc0[r] = fmaf(xv.z, w2x, acc0[r]);  acc1[r] = fmaf(xv.z, w2y, acc1[r]);
        acc0[r] = fmaf(xv.w, w3x, acc0[r]);  acc1[r] = fmaf(xv.w, w3y, acc1[r]);
      }
    }
  } else {
    const bool v0 = (c0 < V_), v1 = (c0 + 1 < V_);
    for (int k = 0; k < D_; k += 4) {
      const float* wp = Ws + (size_t)k * V_;
      float w0x = v0 ? wp[c0]          : 0.f;  float w0y = v1 ? wp[c0 + 1]          : 0.f;
      float w1x = v0 ? wp[V_ + c0]     : 0.f;  float w1y = v1 ? wp[V_ + c0 + 1]     : 0.f;
      float w2x = v0 ? wp[2 * V_ + c0] : 0.f;  float w2y = v1 ? wp[2 * V_ + c0 + 1] : 0.f;
      float w3x = v0 ? wp[3 * V_ + c0] : 0.f;  float w3y = v1 ? wp[3 * V_ + c0 + 1] : 0.f;
#pragma unroll
      for (int r = 0; r < 16; ++r) {
        float4 xv = *(const float4*)&Z[(m0 + r) * D_ + k];
        acc0[r] = fmaf(xv.x, w0x, acc0[r]);  acc1[r] = fmaf(xv.x, w0y, acc1[r]);
        acc0[r] = fmaf(xv.y, w1x, acc0[r]);  acc1[r] = fmaf(xv.y, w1y, acc1[r]);
        acc0[r] = fmaf(xv.z, w2x, acc0[r]);  acc1[r] = fmaf(xv.z, w2y, acc1[r]);
        acc0[r] = fmaf(xv.w, w3x, acc0[r]);  acc1[r] = fmaf(xv.w, w3y, acc1[r]);
      }
    }
  }
#pragma unroll
  for (int r = 0; r < 16; ++r) {
    int m = m0 + r;
    if (c0 < V_)     logits[(size_t)m * V_ + c0]     = acc0[r] + bs[c0];
    if (c0 + 1 < V_) logits[(size_t)m * V_ + c0 + 1] = acc1[r] + bs[c0 + 1];
  }
}

// ---------------- softmax over rows of logits [64, V] ----------------
#define SM_CHUNK 12565  // 4 * 12565 >= V_

__device__ __forceinline__ float waveMax(float v) {
#pragma unroll
  for (int o = 32; o > 0; o >>= 1) v = fmaxf(v, __shfl_xor(v, o, 64));
  return v;
}
__device__ __forceinline__ float waveSum(float v) {
#pragma unroll
  for (int o = 32; o > 0; o >>= 1) v += __shfl_xor(v, o, 64);
  return v;
}

__global__ void k_softmax1(const float* __restrict__ logits, float2* __restrict__ stats) {
  __shared__ float smx[4], ssum[4];
  const int r = blockIdx.x >> 2, q = blockIdx.x & 3;
  const int beg = q * SM_CHUNK;
  const int end = (beg + SM_CHUNK < V_) ? beg + SM_CHUNK : V_;
  const float* row = logits + (size_t)r * V_;

  float mx = -3.4e38f;
  for (int i = beg + threadIdx.x; i < end; i += 256) mx = fmaxf(mx, row[i]);
  mx = waveMax(mx);
  if ((threadIdx.x & 63) == 0) smx[threadIdx.x >> 6] = mx;
  __syncthreads();
  mx = fmaxf(fmaxf(smx[0], smx[1]), fmaxf(smx[2], smx[3]));

  float s = 0.f;
  for (int i = beg + threadIdx.x; i < end; i += 256) s += __expf(row[i] - mx);
  s = waveSum(s);
  if ((threadIdx.x & 63) == 0) ssum[threadIdx.x >> 6] = s;
  __syncthreads();
  s = (ssum[0] + ssum[1]) + (ssum[2] + ssum[3]);

  if (threadIdx.x == 0) stats[blockIdx.x] = make_float2(mx, s);
}

__global__ void k_softmax2(const float* __restrict__ logits, const float2* __restrict__ stats,
                           float* __restrict__ out) {
  const int r = blockIdx.x >> 2, q = blockIdx.x & 3;
  float2 s0 = stats[r * 4 + 0], s1 = stats[r * 4 + 1];
  float2 s2 = stats[r * 4 + 2], s3 = stats[r * 4 + 3];
  float M = fmaxf(fmaxf(s0.x, s1.x), fmaxf(s2.x, s3.x));
  float S = s0.y * __expf(s0.x - M) + s1.y * __expf(s1.x - M)
          + s2.y * __expf(s2.x - M) + s3.y * __expf(s3.x - M);
  float inv = 1.f / S;
  const int beg = q * SM_CHUNK;
  const int end = (beg + SM_CHUNK < V_) ? beg + SM_CHUNK : V_;
  const float* row = logits + (size_t)r * V_;
  float* orow = out + (size_t)r * V_;
  for (int i = beg + threadIdx.x; i < end; i += 256) orow[i] = __expf(row[i] - M) * inv;
}

// ---------------- launch ----------------
extern "C" void kernel_launch(void* const* d_in, const int* in_sizes, int n_in,
                              void* d_out, int out_size, void* d_ws, size_t ws_size,
                              hipStream_t stream) {
  const float* eh   = (const float*)d_in[0];
  const int*   ques = (const int*)d_in[1];
  const void*  mask = d_in[2];
  const float* emb  = (const float*)d_in[3];
  const float* W1   = (const float*)d_in[4];
  const float* b1   = (const float*)d_in[5];
  const float* W2   = (const float*)d_in[6];
  const float* b2   = (const float*)d_in[7];
  const float* A    = (const float*)d_in[8];
  const float* H    = (const float*)d_in[9];
  const float* Ws   = (const float*)d_in[10];
  const float* bs   = (const float*)d_in[11];
  float* out = (float*)d_out;
  char* ws = (char*)d_ws;

  // ws layout (bytes, 256-aligned)
  float*  logits  = (float*)(ws + 0);           // 64*50257*4 = 12,865,792
  float*  entpart = (float*)(ws + 12866048);    // 512*1024*4 = 2,097,152
  float*  entsum  = (float*)(ws + 14963200);    // 4,096
  float*  gpart   = (float*)(ws + 14967296);    // up to 16*64*2048*4 = 4,194,304... (8*64*2048 used)
  float*  hbuf    = (float*)(ws + 19161600);    // 64*2048*4 = 524,288
  float*  qbuf    = (float*)(ws + 19685888);    // 64*1024*4 = 262,144
  float*  ubuf    = (float*)(ws + 19948032);    // 262,144
  float*  zbuf    = (float*)(ws + 20210176);    // 262,144
  float2* stats   = (float2*)(ws + 20472320);   // 256*8 = 2,048

  // 1) ent_sum
  k_ent_partial<<<512, 256, 0, stream>>>(eh, mask, entpart);
  k_ent_reduce<<<4, 256, 0, stream>>>(entpart, entsum);

  // 2) h = relu(emb[question] @ W1 + b1)   [64,2048], K=1024
  k_gemm64<<<dim3(32, 8), 256, 0, stream>>>(nullptr, ques, emb, W1, 1024, 2048, 128, gpart);
  k_reduce_ep<<<512, 256, 0, stream>>>(gpart, 8, 64 * 2048, 2048, b1, nullptr, 1, hbuf);

  // 3) q = h @ W2 + b2                     [64,1024], K=2048
  k_gemm64<<<dim3(16, 16), 256, 0, stream>>>(hbuf, nullptr, nullptr, W2, 2048, 1024, 128, gpart);
  k_reduce_ep<<<256, 256, 0, stream>>>(gpart, 16, 64 * 1024, 1024, b2, nullptr, 2, qbuf);

  // 4) u = (q @ A) * ent_sum               [64,1024]
  k_gemm64<<<dim3(16, 8), 256, 0, stream>>>(qbuf, nullptr, nullptr, A, 1024, 1024, 128, gpart);
  k_reduce_ep<<<256, 256, 0, stream>>>(gpart, 8, 64 * 1024, 1024, entsum, nullptr, 3, ubuf);

  // 5) z = q + u @ H                       [64,1024]
  k_gemm64<<<dim3(16, 8), 256, 0, stream>>>(ubuf, nullptr, nullptr, H, 1024, 1024, 128, gpart);
  k_reduce_ep<<<256, 256, 0, stream>>>(gpart, 8, 64 * 1024, 1024, nullptr, qbuf, 4, zbuf);

  // 6) logits = z @ Ws + bs                [64,V]
  k_gemm_big<<<393, 256, 0, stream>>>(zbuf, Ws, bs, logits);

  // 7) softmax
  k_softmax1<<<256, 256, 0, stream>>>(logits, stats);
  k_softmax2<<<256, 256, 0, stream>>>(logits, stats, out);

  (void)in_sizes; (void)n_in; (void)out_size; (void)ws_size;
}

// Round 3
// 364.371 us; speedup vs baseline: 1.6561x; 1.6561x over previous
//
#include <hip/hip_runtime.h>
#include <stdint.h>

#define V_ 50257
#define D_ 1024
#define F_ 2048
#define B_ 64
#define E_ 512
#define ROWS_ (B_*E_)

typedef __attribute__((ext_vector_type(8))) short bf16x8;
typedef __attribute__((ext_vector_type(4))) float f32x4;

__device__ __forceinline__ unsigned rne1(float a) {
  unsigned u = __float_as_uint(a);
  return (u + 0x7FFFu + ((u >> 16) & 1u)) >> 16;
}

// ---------------- ent_sum: masked row-sum over entity_hiddens ----------------
__global__ void k_ent_partial(const float* __restrict__ eh, const void* __restrict__ mask,
                              float* __restrict__ part) {
  __shared__ int s_mode;
  const int tid = threadIdx.x;
  const uint32_t* mu = (const uint32_t*)mask;
  int f = 0;
  for (int i = tid; i < (ROWS_ / 4); i += 256) {
    uint32_t u = mu[i];
    if (u == 0x3F800000u) f |= 2;
    else if (u & 0xFFFFFF00u) f |= 1;
  }
  if (tid == 0) s_mode = 0;
  __syncthreads();
  if (f) atomicOr(&s_mode, f);
  __syncthreads();
  const int sm = s_mode;
  const int mode = (sm & 1) ? 1 : ((sm & 2) ? 2 : 0);

  float4 acc = make_float4(0.f, 0.f, 0.f, 0.f);
  const float4* eh4 = (const float4*)eh;
  for (int row = blockIdx.x; row < ROWS_; row += gridDim.x) {
    bool on;
    if (mode == 1)      on = ((const unsigned char*)mask)[row] != 0;
    else if (mode == 2) on = ((const float*)mask)[row] != 0.f;
    else                on = ((const int*)mask)[row] != 0;
    if (on) {
      float4 v = eh4[(size_t)row * (D_ / 4) + tid];
      acc.x += v.x; acc.y += v.y; acc.z += v.z; acc.w += v.w;
    }
  }
  ((float4*)part)[(size_t)blockIdx.x * (D_ / 4) + tid] = acc;
}

__global__ void k_ent_reduce(const float* __restrict__ part, float* __restrict__ entsum) {
  int d = blockIdx.x * 256 + threadIdx.x;  // 4 blocks x 256 = 1024
  float s0 = 0.f, s1 = 0.f, s2 = 0.f, s3 = 0.f;
  for (int i = 0; i < 512; i += 4) {
    s0 += part[(size_t)(i    ) * D_ + d];
    s1 += part[(size_t)(i + 1) * D_ + d];
    s2 += part[(size_t)(i + 2) * D_ + d];
    s3 += part[(size_t)(i + 3) * D_ + d];
  }
  entsum[d] = (s0 + s1) + (s2 + s3);
}

// ---------------- small GEMM (M=64), split-K, writes partials ----------------
__global__ void k_gemm64(const float* __restrict__ X, const int* __restrict__ gatherIdx,
                         const float* __restrict__ emb, const float* __restrict__ W,
                         int K, int N, float* __restrict__ part) {
  const int l  = threadIdx.x & 63;
  const int rg = __builtin_amdgcn_readfirstlane((int)(threadIdx.x >> 6));
  const int c  = blockIdx.x * 64 + l;
  const int k0 = blockIdx.y * 64;
  const int m0 = rg * 16;

  const float* Xp = gatherIdx ? emb : X;
  int rb[16];
#pragma unroll
  for (int r = 0; r < 16; ++r) {
    int m = m0 + r;
    rb[r] = gatherIdx ? gatherIdx[m] * K : m * K;
  }

  float acc[16];
#pragma unroll
  for (int r = 0; r < 16; ++r) acc[r] = 0.f;

  for (int k = k0; k < k0 + 64; k += 8) {
    float wv[8];
#pragma unroll
    for (int j = 0; j < 8; ++j) wv[j] = W[(size_t)(k + j) * N + c];
#pragma unroll
    for (int r = 0; r < 16; ++r) {
      float4 x0 = *(const float4*)&Xp[rb[r] + k];
      float4 x1 = *(const float4*)&Xp[rb[r] + k + 4];
      acc[r] = fmaf(x0.x, wv[0], acc[r]);
      acc[r] = fmaf(x0.y, wv[1], acc[r]);
      acc[r] = fmaf(x0.z, wv[2], acc[r]);
      acc[r] = fmaf(x0.w, wv[3], acc[r]);
      acc[r] = fmaf(x1.x, wv[4], acc[r]);
      acc[r] = fmaf(x1.y, wv[5], acc[r]);
      acc[r] = fmaf(x1.z, wv[6], acc[r]);
      acc[r] = fmaf(x1.w, wv[7], acc[r]);
    }
  }
  size_t base = (size_t)blockIdx.y * ((size_t)64 * N);
#pragma unroll
  for (int r = 0; r < 16; ++r) part[base + (size_t)(m0 + r) * N + c] = acc[r];
}

// reduce split-K partials + epilogue.
// mode 1: relu(x+vecB[c]); 2: x+vecB[c]; 3: x*vecB[c]; 4: (x+addend) -> bf16 hi/lo split
__global__ void k_reduce_ep(const float* __restrict__ part, int nsplit, int MN, int N,
                            const float* __restrict__ vecB, const float* __restrict__ addend,
                            int mode, float* __restrict__ dst,
                            unsigned short* __restrict__ dhi, unsigned short* __restrict__ dlo) {
  int idx = blockIdx.x * 256 + threadIdx.x;
  if (idx >= MN) return;
  float s = 0.f;
  for (int i = 0; i < nsplit; ++i) s += part[(size_t)i * MN + idx];
  int c = idx & (N - 1);  // N is a power of two
  if (mode == 1)      { s += vecB[c]; s = s > 0.f ? s : 0.f; dst[idx] = s; }
  else if (mode == 2) { s += vecB[c]; dst[idx] = s; }
  else if (mode == 3) { s *= vecB[c]; dst[idx] = s; }
  else {
    s += addend[idx];
    unsigned hi = rne1(s);
    float hif = __uint_as_float(hi << 16);
    dhi[idx] = (unsigned short)hi;
    dlo[idx] = (unsigned short)rne1(s - hif);
  }
}

// ---------------- big GEMM: logits = Z[64,1024] @ Ws[1024,V] + bs, split-bf16 MFMA -------
// Z pre-split into zhi/zlo (bf16); Ws split hi/lo in-register. acc = Ahi*Bhi + Ahi*Blo
// + Alo*Bhi (residual Alo*Blo ~ 2^-18 rel). Fragment addressing identical to the
// round-2-verified map: A row = lane&15, k-chunk = (lane>>4)*8; C row = g*4+i, col = lane&15.
__global__ __launch_bounds__(256) void k_gemm_big(const unsigned short* __restrict__ zhi,
                                                  const unsigned short* __restrict__ zlo,
                                                  const float* __restrict__ Ws,
                                                  const float* __restrict__ bs,
                                                  float* __restrict__ logits) {
  const int l   = threadIdx.x & 63;
  const int w   = threadIdx.x >> 6;
  const int col = l & 15;
  const int g   = l >> 4;  // k-chunk g*8..g*8+7
  const int c   = blockIdx.x * 64 + w * 16 + col;
  const int cc  = c < V_ ? c : V_ - 1;

  f32x4 acc0 = {0.f, 0.f, 0.f, 0.f};
  f32x4 acc1 = {0.f, 0.f, 0.f, 0.f};
  f32x4 acc2 = {0.f, 0.f, 0.f, 0.f};
  f32x4 acc3 = {0.f, 0.f, 0.f, 0.f};

#pragma unroll 2
  for (int k0 = 0; k0 < D_; k0 += 32) {
    const float* wp = Ws + (size_t)(k0 + g * 8) * V_ + cc;
    float f[8];
#pragma unroll
    for (int j = 0; j < 8; ++j) f[j] = wp[(size_t)j * V_];

    union { bf16x8 v; unsigned u[4]; } bh, bl;
#pragma unroll
    for (int j = 0; j < 4; ++j) {
      unsigned h0 = rne1(f[2 * j]);
      unsigned h1 = rne1(f[2 * j + 1]);
      float h0f = __uint_as_float(h0 << 16);
      float h1f = __uint_as_float(h1 << 16);
      bh.u[j] = h0 | (h1 << 16);
      bl.u[j] = rne1(f[2 * j] - h0f) | (rne1(f[2 * j + 1] - h1f) << 16);
    }

    const int aoff = col * D_ + k0 + g * 8;
    bf16x8 ah0 = *(const bf16x8*)(zhi + aoff);
    bf16x8 ah1 = *(const bf16x8*)(zhi + aoff + 16 * D_);
    bf16x8 ah2 = *(const bf16x8*)(zhi + aoff + 32 * D_);
    bf16x8 ah3 = *(const bf16x8*)(zhi + aoff + 48 * D_);
    bf16x8 al0 = *(const bf16x8*)(zlo + aoff);
    bf16x8 al1 = *(const bf16x8*)(zlo + aoff + 16 * D_);
    bf16x8 al2 = *(const bf16x8*)(zlo + aoff + 32 * D_);
    bf16x8 al3 = *(const bf16x8*)(zlo + aoff + 48 * D_);

    acc0 = __builtin_amdgcn_mfma_f32_16x16x32_bf16(ah0, bh.v, acc0, 0, 0, 0);
    acc1 = __builtin_amdgcn_mfma_f32_16x16x32_bf16(ah1, bh.v, acc1, 0, 0, 0);
    acc2 = __builtin_amdgcn_mfma_f32_16x16x32_bf16(ah2, bh.v, acc2, 0, 0, 0);
    acc3 = __builtin_amdgcn_mfma_f32_16x16x32_bf16(ah3, bh.v, acc3, 0, 0, 0);
    acc0 = __builtin_amdgcn_mfma_f32_16x16x32_bf16(ah0, bl.v, acc0, 0, 0, 0);
    acc1 = __builtin_amdgcn_mfma_f32_16x16x32_bf16(ah1, bl.v, acc1, 0, 0, 0);
    acc2 = __builtin_amdgcn_mfma_f32_16x16x32_bf16(ah2, bl.v, acc2, 0, 0, 0);
    acc3 = __builtin_amdgcn_mfma_f32_16x16x32_bf16(ah3, bl.v, acc3, 0, 0, 0);
    acc0 = __builtin_amdgcn_mfma_f32_16x16x32_bf16(al0, bh.v, acc0, 0, 0, 0);
    acc1 = __builtin_amdgcn_mfma_f32_16x16x32_bf16(al1, bh.v, acc1, 0, 0, 0);
    acc2 = __builtin_amdgcn_mfma_f32_16x16x32_bf16(al2, bh.v, acc2, 0, 0, 0);
    acc3 = __builtin_amdgcn_mfma_f32_16x16x32_bf16(al3, bh.v, acc3, 0, 0, 0);
  }

  if (c < V_) {
    float bias = bs[c];
#pragma unroll
    for (int i = 0; i < 4; ++i) logits[(size_t)(g * 4 + i) * V_ + c]      = acc0[i] + bias;
#pragma unroll
    for (int i = 0; i < 4; ++i) logits[(size_t)(16 + g * 4 + i) * V_ + c] = acc1[i] + bias;
#pragma unroll
    for (int i = 0; i < 4; ++i) logits[(size_t)(32 + g * 4 + i) * V_ + c] = acc2[i] + bias;
#pragma unroll
    for (int i = 0; i < 4; ++i) logits[(size_t)(48 + g * 4 + i) * V_ + c] = acc3[i] + bias;
  }
}

// ---------------- softmax over rows of logits [64, V] ----------------
#define SM_CHUNK 12565  // 4 * 12565 >= V_

__device__ __forceinline__ float waveMax(float v) {
#pragma unroll
  for (int o = 32; o > 0; o >>= 1) v = fmaxf(v, __shfl_xor(v, o, 64));
  return v;
}
__device__ __forceinline__ float waveSum(float v) {
#pragma unroll
  for (int o = 32; o > 0; o >>= 1) v += __shfl_xor(v, o, 64);
  return v;
}

__global__ void k_softmax1(const float* __restrict__ logits, float2* __restrict__ stats) {
  __shared__ float smx[4], ssum[4];
  const int r = blockIdx.x >> 2, q = blockIdx.x & 3;
  const int beg = q * SM_CHUNK;
  const int end = (beg + SM_CHUNK < V_) ? beg + SM_CHUNK : V_;
  const float* row = logits + (size_t)r * V_;

  float mx = -3.4e38f;
  for (int i = beg + threadIdx.x; i < end; i += 256) mx = fmaxf(mx, row[i]);
  mx = waveMax(mx);
  if ((threadIdx.x & 63) == 0) smx[threadIdx.x >> 6] = mx;
  __syncthreads();
  mx = fmaxf(fmaxf(smx[0], smx[1]), fmaxf(smx[2], smx[3]));

  float s = 0.f;
  for (int i = beg + threadIdx.x; i < end; i += 256) s += __expf(row[i] - mx);
  s = waveSum(s);
  if ((threadIdx.x & 63) == 0) ssum[threadIdx.x >> 6] = s;
  __syncthreads();
  s = (ssum[0] + ssum[1]) + (ssum[2] + ssum[3]);

  if (threadIdx.x == 0) stats[blockIdx.x] = make_float2(mx, s);
}

__global__ void k_softmax2(const float* __restrict__ logits, const float2* __restrict__ stats,
                           float* __restrict__ out) {
  const int r = blockIdx.x >> 2, q = blockIdx.x & 3;
  float2 s0 = stats[r * 4 + 0], s1 = stats[r * 4 + 1];
  float2 s2 = stats[r * 4 + 2], s3 = stats[r * 4 + 3];
  float M = fmaxf(fmaxf(s0.x, s1.x), fmaxf(s2.x, s3.x));
  float S = s0.y * __expf(s0.x - M) + s1.y * __expf(s1.x - M)
          + s2.y * __expf(s2.x - M) + s3.y * __expf(s3.x - M);
  float inv = 1.f / S;
  const int beg = q * SM_CHUNK;
  const int end = (beg + SM_CHUNK < V_) ? beg + SM_CHUNK : V_;
  const float* row = logits + (size_t)r * V_;
  float* orow = out + (size_t)r * V_;
  for (int i = beg + threadIdx.x; i < end; i += 256) orow[i] = __expf(row[i] - M) * inv;
}

// ---------------- launch ----------------
extern "C" void kernel_launch(void* const* d_in, const int* in_sizes, int n_in,
                              void* d_out, int out_size, void* d_ws, size_t ws_size,
                              hipStream_t stream) {
  const float* eh   = (const float*)d_in[0];
  const int*   ques = (const int*)d_in[1];
  const void*  mask = d_in[2];
  const float* emb  = (const float*)d_in[3];
  const float* W1   = (const float*)d_in[4];
  const float* b1   = (const float*)d_in[5];
  const float* W2   = (const float*)d_in[6];
  const float* b2   = (const float*)d_in[7];
  const float* A    = (const float*)d_in[8];
  const float* H    = (const float*)d_in[9];
  const float* Ws   = (const float*)d_in[10];
  const float* bs   = (const float*)d_in[11];
  float* out = (float*)d_out;
  char* ws = (char*)d_ws;

  // ws layout (bytes, 256-aligned). gpart aliases logits (temporally disjoint).
  float*          logits  = (float*)(ws + 0);           // 64*50257*4 = 12,865,792
  float*          gpart   = (float*)(ws + 0);           // max 8,388,608 (aliased)
  float*          entpart = (float*)(ws + 12866048);    // 2,097,152
  float*          entsum  = (float*)(ws + 14963200);    // 4,096
  float*          hbuf    = (float*)(ws + 14967296);    // 524,288
  float*          qbuf    = (float*)(ws + 15491584);    // 262,144
  float*          ubuf    = (float*)(ws + 15753728);    // 262,144
  unsigned short* zhi16   = (unsigned short*)(ws + 16015872);  // 131,072
  unsigned short* zlo16   = (unsigned short*)(ws + 16146944);  // 131,072
  float2*         stats   = (float2*)(ws + 16278016);   // 2,048

  // 1) ent_sum
  k_ent_partial<<<512, 256, 0, stream>>>(eh, mask, entpart);
  k_ent_reduce<<<4, 256, 0, stream>>>(entpart, entsum);

  // 2) h = relu(emb[question] @ W1 + b1)   [64,2048], K=1024, split 16
  k_gemm64<<<dim3(32, 16), 256, 0, stream>>>(nullptr, ques, emb, W1, 1024, 2048, gpart);
  k_reduce_ep<<<512, 256, 0, stream>>>(gpart, 16, 64 * 2048, 2048, b1, nullptr, 1, hbuf, nullptr, nullptr);

  // 3) q = h @ W2 + b2                     [64,1024], K=2048, split 32
  k_gemm64<<<dim3(16, 32), 256, 0, stream>>>(hbuf, nullptr, nullptr, W2, 2048, 1024, gpart);
  k_reduce_ep<<<256, 256, 0, stream>>>(gpart, 32, 64 * 1024, 1024, b2, nullptr, 2, qbuf, nullptr, nullptr);

  // 4) u = (q @ A) * ent_sum               [64,1024], split 16
  k_gemm64<<<dim3(16, 16), 256, 0, stream>>>(qbuf, nullptr, nullptr, A, 1024, 1024, gpart);
  k_reduce_ep<<<256, 256, 0, stream>>>(gpart, 16, 64 * 1024, 1024, entsum, nullptr, 3, ubuf, nullptr, nullptr);

  // 5) z = q + u @ H (-> bf16 hi/lo)       [64,1024], split 16
  k_gemm64<<<dim3(16, 16), 256, 0, stream>>>(ubuf, nullptr, nullptr, H, 1024, 1024, gpart);
  k_reduce_ep<<<256, 256, 0, stream>>>(gpart, 16, 64 * 1024, 1024, nullptr, qbuf, 4, nullptr, zhi16, zlo16);

  // 6) logits = z @ Ws + bs                [64,V], split-bf16 MFMA
  k_gemm_big<<<786, 256, 0, stream>>>(zhi16, zlo16, Ws, bs, logits);

  // 7) softmax
  k_softmax1<<<256, 256, 0, stream>>>(logits, stats);
  k_softmax2<<<256, 256, 0, stream>>>(logits, stats, out);

  (void)in_sizes; (void)n_in; (void)out_size; (void)ws_size;
}

// Round 4
// 363.102 us; speedup vs baseline: 1.6618x; 1.0035x over previous
//
#include <hip/hip_runtime.h>
#include <stdint.h>

#define V_ 50257
#define D_ 1024
#define F_ 2048
#define B_ 64
#define E_ 512
#define ROWS_ (B_*E_)

typedef __attribute__((ext_vector_type(8))) short bf16x8;
typedef __attribute__((ext_vector_type(4))) float f32x4;

__device__ __forceinline__ unsigned rne1(float a) {
  unsigned u = __float_as_uint(a);
  return (u + 0x7FFFu + ((u >> 16) & 1u)) >> 16;
}

__device__ __forceinline__ float waveMax(float v) {
#pragma unroll
  for (int o = 32; o > 0; o >>= 1) v = fmaxf(v, __shfl_xor(v, o, 64));
  return v;
}
__device__ __forceinline__ float waveSum(float v) {
#pragma unroll
  for (int o = 32; o > 0; o >>= 1) v += __shfl_xor(v, o, 64);
  return v;
}

// ---------------- device bodies ----------------

// masked row-sum partial over entity_hiddens; one block = one row-stripe
__device__ __forceinline__ void ent_partial_body(int bid, const float* __restrict__ eh,
                                                 const void* __restrict__ mask,
                                                 float* __restrict__ part) {
  __shared__ int s_mode;
  const int tid = threadIdx.x;
  const uint32_t* mu = (const uint32_t*)mask;
  int f = 0;
  for (int i = tid; i < (ROWS_ / 4); i += 256) {
    uint32_t u = mu[i];
    if (u == 0x3F800000u) f |= 2;
    else if (u & 0xFFFFFF00u) f |= 1;
  }
  if (tid == 0) s_mode = 0;
  __syncthreads();
  if (f) atomicOr(&s_mode, f);
  __syncthreads();
  const int sm = s_mode;
  const int mode = (sm & 1) ? 1 : ((sm & 2) ? 2 : 0);

  float4 acc = make_float4(0.f, 0.f, 0.f, 0.f);
  const float4* eh4 = (const float4*)eh;
  for (int row = bid; row < ROWS_; row += 512) {
    bool on;
    if (mode == 1)      on = ((const unsigned char*)mask)[row] != 0;
    else if (mode == 2) on = ((const float*)mask)[row] != 0.f;
    else                on = ((const int*)mask)[row] != 0;
    if (on) {
      float4 v = eh4[(size_t)row * (D_ / 4) + tid];
      acc.x += v.x; acc.y += v.y; acc.z += v.z; acc.w += v.w;
    }
  }
  ((float4*)part)[(size_t)bid * (D_ / 4) + tid] = acc;
}

__device__ __forceinline__ void ent_reduce_body(int bid, const float* __restrict__ part,
                                                float* __restrict__ entsum) {
  int d = bid * 256 + threadIdx.x;  // 4 blocks x 256 = 1024
  float s0 = 0.f, s1 = 0.f, s2 = 0.f, s3 = 0.f;
  for (int i = 0; i < 512; i += 4) {
    s0 += part[(size_t)(i    ) * D_ + d];
    s1 += part[(size_t)(i + 1) * D_ + d];
    s2 += part[(size_t)(i + 2) * D_ + d];
    s3 += part[(size_t)(i + 3) * D_ + d];
  }
  entsum[d] = (s0 + s1) + (s2 + s3);
}

// small GEMM (M=64), split-K partials. 256 thr = 64 cols x 4 row-groups(16 rows).
__device__ __forceinline__ void gemm64_body(int bx, int by, const float* __restrict__ X,
                                            const int* __restrict__ gatherIdx,
                                            const float* __restrict__ emb,
                                            const float* __restrict__ W,
                                            int K, int N, int KB, float* __restrict__ part) {
  const int l  = threadIdx.x & 63;
  const int rg = __builtin_amdgcn_readfirstlane((int)(threadIdx.x >> 6));
  const int c  = bx * 64 + l;
  const int k0 = by * KB;
  const int m0 = rg * 16;

  const float* Xp = gatherIdx ? emb : X;
  int rb[16];
#pragma unroll
  for (int r = 0; r < 16; ++r) {
    int m = m0 + r;
    rb[r] = gatherIdx ? gatherIdx[m] * K : m * K;
  }

  float acc[16];
#pragma unroll
  for (int r = 0; r < 16; ++r) acc[r] = 0.f;

  for (int k = k0; k < k0 + KB; k += 8) {
    float wv[8];
#pragma unroll
    for (int j = 0; j < 8; ++j) wv[j] = W[(size_t)(k + j) * N + c];
#pragma unroll
    for (int r = 0; r < 16; ++r) {
      float4 x0 = *(const float4*)&Xp[rb[r] + k];
      float4 x1 = *(const float4*)&Xp[rb[r] + k + 4];
      acc[r] = fmaf(x0.x, wv[0], acc[r]);
      acc[r] = fmaf(x0.y, wv[1], acc[r]);
      acc[r] = fmaf(x0.z, wv[2], acc[r]);
      acc[r] = fmaf(x0.w, wv[3], acc[r]);
      acc[r] = fmaf(x1.x, wv[4], acc[r]);
      acc[r] = fmaf(x1.y, wv[5], acc[r]);
      acc[r] = fmaf(x1.z, wv[6], acc[r]);
      acc[r] = fmaf(x1.w, wv[7], acc[r]);
    }
  }
  size_t base = (size_t)by * ((size_t)64 * N);
#pragma unroll
  for (int r = 0; r < 16; ++r) part[base + (size_t)(m0 + r) * N + c] = acc[r];
}

// reduce split-K partials + epilogue.
// mode 1: relu(x+vecB[c]); 2: x+vecB[c]; 3: x*vecB[c]; 4: (x+addend) -> bf16 hi/lo split
__device__ __forceinline__ void reduce_ep_body(int bid, const float* __restrict__ part,
                                               int nsplit, int MN, int N,
                                               const float* __restrict__ vecB,
                                               const float* __restrict__ addend,
                                               int mode, float* __restrict__ dst,
                                               unsigned short* __restrict__ dhi,
                                               unsigned short* __restrict__ dlo) {
  int idx = bid * 256 + threadIdx.x;
  if (idx >= MN) return;
  float s = 0.f;
  for (int i = 0; i < nsplit; ++i) s += part[(size_t)i * MN + idx];
  int c = idx & (N - 1);  // N is a power of two
  if (mode == 1)      { s += vecB[c]; s = s > 0.f ? s : 0.f; dst[idx] = s; }
  else if (mode == 2) { s += vecB[c]; dst[idx] = s; }
  else if (mode == 3) { s *= vecB[c]; dst[idx] = s; }
  else {
    s += addend[idx];
    unsigned hi = rne1(s);
    float hif = __uint_as_float(hi << 16);
    dhi[idx] = (unsigned short)hi;
    dlo[idx] = (unsigned short)rne1(s - hif);
  }
}

// ---------------- fused phase kernels ----------------
__global__ void k_p1(const float* __restrict__ eh, const void* __restrict__ mask,
                     float* __restrict__ entpart, const int* __restrict__ ques,
                     const float* __restrict__ emb, const float* __restrict__ W1,
                     float* __restrict__ gpart) {
  int bid = blockIdx.x;
  if (bid < 512) ent_partial_body(bid, eh, mask, entpart);
  else {
    int b2 = bid - 512;
    gemm64_body(b2 & 31, b2 >> 5, nullptr, ques, emb, W1, 1024, 2048, 64, gpart);
  }
}

__global__ void k_p2(const float* __restrict__ entpart, float* __restrict__ entsum,
                     const float* __restrict__ gpart, const float* __restrict__ b1,
                     float* __restrict__ hbuf) {
  int bid = blockIdx.x;
  if (bid < 4) ent_reduce_body(bid, entpart, entsum);
  else reduce_ep_body(bid - 4, gpart, 16, 64 * 2048, 2048, b1, nullptr, 1, hbuf, nullptr, nullptr);
}

__global__ void k_gemm64(const float* __restrict__ X, const float* __restrict__ W,
                         int K, int N, int KB, float* __restrict__ part) {
  gemm64_body(blockIdx.x, blockIdx.y, X, nullptr, nullptr, W, K, N, KB, part);
}

__global__ void k_reduce_ep(const float* __restrict__ part, int nsplit, int MN, int N,
                            const float* __restrict__ vecB, const float* __restrict__ addend,
                            int mode, float* __restrict__ dst,
                            unsigned short* __restrict__ dhi, unsigned short* __restrict__ dlo) {
  reduce_ep_body(blockIdx.x, part, nsplit, MN, N, vecB, addend, mode, dst, dhi, dlo);
}

// ---------------- big GEMM: logits = Z[64,1024] @ Ws[1024,V] + bs, split-bf16 MFMA -------
// 512 thr = 8 waves: wave = (mh = w>>2 selecting rows mh*32..mh*32+31, ww = w&3 selecting
// 16-col group). Each wave: 2 M-tiles x 1 N-tile, full K -> 6288 waves total for parallelism.
// Fragment map identical to verified round-2/3 kernel.
__global__ __launch_bounds__(512) void k_gemm_big(const unsigned short* __restrict__ zhi,
                                                  const unsigned short* __restrict__ zlo,
                                                  const float* __restrict__ Ws,
                                                  const float* __restrict__ bs,
                                                  float* __restrict__ logits) {
  const int l   = threadIdx.x & 63;
  const int w   = threadIdx.x >> 6;
  const int ww  = w & 3;
  const int mh  = w >> 2;            // 0: rows 0-31, 1: rows 32-63
  const int col = l & 15;
  const int g   = l >> 4;            // k-chunk g*8..g*8+7
  const int c   = blockIdx.x * 64 + ww * 16 + col;
  const int cc  = c < V_ ? c : V_ - 1;
  const int mb  = mh * 32;

  f32x4 acc0 = {0.f, 0.f, 0.f, 0.f};
  f32x4 acc1 = {0.f, 0.f, 0.f, 0.f};

#pragma unroll 2
  for (int k0 = 0; k0 < D_; k0 += 32) {
    const float* wp = Ws + (size_t)(k0 + g * 8) * V_ + cc;
    float f[8];
#pragma unroll
    for (int j = 0; j < 8; ++j) f[j] = wp[(size_t)j * V_];

    union { bf16x8 v; unsigned u[4]; } bh, bl;
#pragma unroll
    for (int j = 0; j < 4; ++j) {
      unsigned h0 = rne1(f[2 * j]);
      unsigned h1 = rne1(f[2 * j + 1]);
      float h0f = __uint_as_float(h0 << 16);
      float h1f = __uint_as_float(h1 << 16);
      bh.u[j] = h0 | (h1 << 16);
      bl.u[j] = rne1(f[2 * j] - h0f) | (rne1(f[2 * j + 1] - h1f) << 16);
    }

    const int aoff = col * D_ + k0 + g * 8;
    bf16x8 ah0 = *(const bf16x8*)(zhi + aoff + (size_t)mb * D_);
    bf16x8 ah1 = *(const bf16x8*)(zhi + aoff + (size_t)(mb + 16) * D_);
    bf16x8 al0 = *(const bf16x8*)(zlo + aoff + (size_t)mb * D_);
    bf16x8 al1 = *(const bf16x8*)(zlo + aoff + (size_t)(mb + 16) * D_);

    acc0 = __builtin_amdgcn_mfma_f32_16x16x32_bf16(ah0, bh.v, acc0, 0, 0, 0);
    acc1 = __builtin_amdgcn_mfma_f32_16x16x32_bf16(ah1, bh.v, acc1, 0, 0, 0);
    acc0 = __builtin_amdgcn_mfma_f32_16x16x32_bf16(ah0, bl.v, acc0, 0, 0, 0);
    acc1 = __builtin_amdgcn_mfma_f32_16x16x32_bf16(ah1, bl.v, acc1, 0, 0, 0);
    acc0 = __builtin_amdgcn_mfma_f32_16x16x32_bf16(al0, bh.v, acc0, 0, 0, 0);
    acc1 = __builtin_amdgcn_mfma_f32_16x16x32_bf16(al1, bh.v, acc1, 0, 0, 0);
  }

  if (c < V_) {
    float bias = bs[c];
#pragma unroll
    for (int i = 0; i < 4; ++i) logits[(size_t)(mb + g * 4 + i) * V_ + c]      = acc0[i] + bias;
#pragma unroll
    for (int i = 0; i < 4; ++i) logits[(size_t)(mb + 16 + g * 4 + i) * V_ + c] = acc1[i] + bias;
  }
}

// ---------------- fused softmax: one block per row ----------------
__global__ __launch_bounds__(1024) void k_softmax(const float* __restrict__ logits,
                                                  float* __restrict__ out) {
  __shared__ float sred[16];
  __shared__ float s_mx, s_inv;
  const int tid = threadIdx.x;
  const float* row = logits + (size_t)blockIdx.x * V_;
  float* orow = out + (size_t)blockIdx.x * V_;

  float mx = -3.4e38f;
  for (int i = tid; i < V_; i += 1024) mx = fmaxf(mx, row[i]);
  mx = waveMax(mx);
  if ((tid & 63) == 0) sred[tid >> 6] = mx;
  __syncthreads();
  if (tid == 0) {
    float m = sred[0];
#pragma unroll
    for (int i = 1; i < 16; ++i) m = fmaxf(m, sred[i]);
    s_mx = m;
  }
  __syncthreads();
  const float M = s_mx;

  float s = 0.f;
  for (int i = tid; i < V_; i += 1024) s += __expf(row[i] - M);
  s = waveSum(s);
  if ((tid & 63) == 0) sred[tid >> 6] = s;
  __syncthreads();
  if (tid == 0) {
    float t = 0.f;
#pragma unroll
    for (int i = 0; i < 16; ++i) t += sred[i];
    s_inv = 1.f / t;
  }
  __syncthreads();
  const float inv = s_inv;
  for (int i = tid; i < V_; i += 1024) orow[i] = __expf(row[i] - M) * inv;
}

// ---------------- launch ----------------
extern "C" void kernel_launch(void* const* d_in, const int* in_sizes, int n_in,
                              void* d_out, int out_size, void* d_ws, size_t ws_size,
                              hipStream_t stream) {
  const float* eh   = (const float*)d_in[0];
  const int*   ques = (const int*)d_in[1];
  const void*  mask = d_in[2];
  const float* emb  = (const float*)d_in[3];
  const float* W1   = (const float*)d_in[4];
  const float* b1   = (const float*)d_in[5];
  const float* W2   = (const float*)d_in[6];
  const float* b2   = (const float*)d_in[7];
  const float* A    = (const float*)d_in[8];
  const float* H    = (const float*)d_in[9];
  const float* Ws   = (const float*)d_in[10];
  const float* bs   = (const float*)d_in[11];
  float* out = (float*)d_out;
  char* ws = (char*)d_ws;

  // ws layout (bytes). gpart aliases logits (temporally disjoint).
  float*          logits  = (float*)(ws + 0);           // 64*50257*4 = 12,865,792
  float*          gpart   = (float*)(ws + 0);           // max 8,388,608 (aliased)
  float*          entpart = (float*)(ws + 12866048);    // 2,097,152
  float*          entsum  = (float*)(ws + 14963200);    // 4,096
  float*          hbuf    = (float*)(ws + 14967296);    // 524,288
  float*          qbuf    = (float*)(ws + 15491584);    // 262,144
  float*          ubuf    = (float*)(ws + 15753728);    // 262,144
  unsigned short* zhi16   = (unsigned short*)(ws + 16015872);  // 131,072
  unsigned short* zlo16   = (unsigned short*)(ws + 16146944);  // 131,072

  // P1: ent_partial (512 blocks) || h-gemm partials (512 blocks)
  k_p1<<<1024, 256, 0, stream>>>(eh, mask, entpart, ques, emb, W1, gpart);
  // P2: ent_reduce (4) || h = relu(.+b1) (512)
  k_p2<<<516, 256, 0, stream>>>(entpart, entsum, gpart, b1, hbuf);

  // P3/P4: q = h @ W2 + b2                 [64,1024], K=2048, split 32
  k_gemm64<<<dim3(16, 32), 256, 0, stream>>>(hbuf, W2, 2048, 1024, 64, gpart);
  k_reduce_ep<<<256, 256, 0, stream>>>(gpart, 32, 64 * 1024, 1024, b2, nullptr, 2, qbuf, nullptr, nullptr);

  // P5/P6: u = (q @ A) * ent_sum           [64,1024], split 16
  k_gemm64<<<dim3(16, 16), 256, 0, stream>>>(qbuf, A, 1024, 1024, 64, gpart);
  k_reduce_ep<<<256, 256, 0, stream>>>(gpart, 16, 64 * 1024, 1024, entsum, nullptr, 3, ubuf, nullptr, nullptr);

  // P7/P8: z = q + u @ H (-> bf16 hi/lo)   [64,1024], split 16
  k_gemm64<<<dim3(16, 16), 256, 0, stream>>>(ubuf, H, 1024, 1024, 64, gpart);
  k_reduce_ep<<<256, 256, 0, stream>>>(gpart, 16, 64 * 1024, 1024, nullptr, qbuf, 4, nullptr, zhi16, zlo16);

  // P9: logits = z @ Ws + bs               [64,V], split-bf16 MFMA, 8-wave blocks
  k_gemm_big<<<786, 512, 0, stream>>>(zhi16, zlo16, Ws, bs, logits);

  // P10: softmax (one block per row)
  k_softmax<<<64, 1024, 0, stream>>>(logits, out);

  (void)in_sizes; (void)n_in; (void)out_size; (void)ws_size;
}

// Round 5
// 342.839 us; speedup vs baseline: 1.7601x; 1.0591x over previous
//
#include <hip/hip_runtime.h>
#include <stdint.h>

#define V_ 50257
#define D_ 1024
#define F_ 2048
#define B_ 64
#define E_ 512
#define ROWS_ (B_*E_)

typedef __attribute__((ext_vector_type(8))) short bf16x8;
typedef __attribute__((ext_vector_type(4))) float f32x4;

__device__ __forceinline__ unsigned rne1(float a) {
  unsigned u = __float_as_uint(a);
  return (u + 0x7FFFu + ((u >> 16) & 1u)) >> 16;
}

__device__ __forceinline__ float waveMax(float v) {
#pragma unroll
  for (int o = 32; o > 0; o >>= 1) v = fmaxf(v, __shfl_xor(v, o, 64));
  return v;
}
__device__ __forceinline__ float waveSum(float v) {
#pragma unroll
  for (int o = 32; o > 0; o >>= 1) v += __shfl_xor(v, o, 64);
  return v;
}

// ---------------- device bodies ----------------

// masked row-sum partial over entity_hiddens; one block = one row-stripe
__device__ __forceinline__ void ent_partial_body(int bid, const float* __restrict__ eh,
                                                 const void* __restrict__ mask,
                                                 float* __restrict__ part) {
  __shared__ int s_mode;
  const int tid = threadIdx.x;
  const uint32_t* mu = (const uint32_t*)mask;
  int f = 0;
  for (int i = tid; i < (ROWS_ / 4); i += 256) {
    uint32_t u = mu[i];
    if (u == 0x3F800000u) f |= 2;
    else if (u & 0xFFFFFF00u) f |= 1;
  }
  if (tid == 0) s_mode = 0;
  __syncthreads();
  if (f) atomicOr(&s_mode, f);
  __syncthreads();
  const int sm = s_mode;
  const int mode = (sm & 1) ? 1 : ((sm & 2) ? 2 : 0);

  float4 acc = make_float4(0.f, 0.f, 0.f, 0.f);
  const float4* eh4 = (const float4*)eh;
  for (int row = bid; row < ROWS_; row += 512) {
    bool on;
    if (mode == 1)      on = ((const unsigned char*)mask)[row] != 0;
    else if (mode == 2) on = ((const float*)mask)[row] != 0.f;
    else                on = ((const int*)mask)[row] != 0;
    if (on) {
      float4 v = eh4[(size_t)row * (D_ / 4) + tid];
      acc.x += v.x; acc.y += v.y; acc.z += v.z; acc.w += v.w;
    }
  }
  ((float4*)part)[(size_t)bid * (D_ / 4) + tid] = acc;
}

__device__ __forceinline__ void ent_reduce_body(int bid, const float* __restrict__ part,
                                                float* __restrict__ entsum) {
  int d = bid * 256 + threadIdx.x;  // 4 blocks x 256 = 1024
  float s0 = 0.f, s1 = 0.f, s2 = 0.f, s3 = 0.f;
  for (int i = 0; i < 512; i += 4) {
    s0 += part[(size_t)(i    ) * D_ + d];
    s1 += part[(size_t)(i + 1) * D_ + d];
    s2 += part[(size_t)(i + 2) * D_ + d];
    s3 += part[(size_t)(i + 3) * D_ + d];
  }
  entsum[d] = (s0 + s1) + (s2 + s3);
}

// small GEMM (M=64), split-K partials. 256 thr = 64 cols x 4 row-groups(16 rows).
__device__ __forceinline__ void gemm64_body(int bx, int by, const float* __restrict__ X,
                                            const int* __restrict__ gatherIdx,
                                            const float* __restrict__ emb,
                                            const float* __restrict__ W,
                                            int K, int N, int KB, float* __restrict__ part) {
  const int l  = threadIdx.x & 63;
  const int rg = __builtin_amdgcn_readfirstlane((int)(threadIdx.x >> 6));
  const int c  = bx * 64 + l;
  const int k0 = by * KB;
  const int m0 = rg * 16;

  const float* Xp = gatherIdx ? emb : X;
  int rb[16];
#pragma unroll
  for (int r = 0; r < 16; ++r) {
    int m = m0 + r;
    rb[r] = gatherIdx ? gatherIdx[m] * K : m * K;
  }

  float acc[16];
#pragma unroll
  for (int r = 0; r < 16; ++r) acc[r] = 0.f;

  for (int k = k0; k < k0 + KB; k += 8) {
    float wv[8];
#pragma unroll
    for (int j = 0; j < 8; ++j) wv[j] = W[(size_t)(k + j) * N + c];
#pragma unroll
    for (int r = 0; r < 16; ++r) {
      float4 x0 = *(const float4*)&Xp[rb[r] + k];
      float4 x1 = *(const float4*)&Xp[rb[r] + k + 4];
      acc[r] = fmaf(x0.x, wv[0], acc[r]);
      acc[r] = fmaf(x0.y, wv[1], acc[r]);
      acc[r] = fmaf(x0.z, wv[2], acc[r]);
      acc[r] = fmaf(x0.w, wv[3], acc[r]);
      acc[r] = fmaf(x1.x, wv[4], acc[r]);
      acc[r] = fmaf(x1.y, wv[5], acc[r]);
      acc[r] = fmaf(x1.z, wv[6], acc[r]);
      acc[r] = fmaf(x1.w, wv[7], acc[r]);
    }
  }
  size_t base = (size_t)by * ((size_t)64 * N);
#pragma unroll
  for (int r = 0; r < 16; ++r) part[base + (size_t)(m0 + r) * N + c] = acc[r];
}

// reduce split-K partials + epilogue.
// mode 1: relu(x+vecB[c]); 2: x+vecB[c]; 3: x*vecB[c]; 4: (x+addend) -> bf16 hi/lo split
__device__ __forceinline__ void reduce_ep_body(int bid, const float* __restrict__ part,
                                               int nsplit, int MN, int N,
                                               const float* __restrict__ vecB,
                                               const float* __restrict__ addend,
                                               int mode, float* __restrict__ dst,
                                               unsigned short* __restrict__ dhi,
                                               unsigned short* __restrict__ dlo) {
  int idx = bid * 256 + threadIdx.x;
  if (idx >= MN) return;
  float s = 0.f;
  for (int i = 0; i < nsplit; ++i) s += part[(size_t)i * MN + idx];
  int c = idx & (N - 1);  // N is a power of two
  if (mode == 1)      { s += vecB[c]; s = s > 0.f ? s : 0.f; dst[idx] = s; }
  else if (mode == 2) { s += vecB[c]; dst[idx] = s; }
  else if (mode == 3) { s *= vecB[c]; dst[idx] = s; }
  else {
    s += addend[idx];
    unsigned hi = rne1(s);
    float hif = __uint_as_float(hi << 16);
    dhi[idx] = (unsigned short)hi;
    dlo[idx] = (unsigned short)rne1(s - hif);
  }
}

// ---------------- fused phase kernels ----------------
__global__ void k_p1(const float* __restrict__ eh, const void* __restrict__ mask,
                     float* __restrict__ entpart, const int* __restrict__ ques,
                     const float* __restrict__ emb, const float* __restrict__ W1,
                     float* __restrict__ gpart) {
  int bid = blockIdx.x;
  if (bid < 512) ent_partial_body(bid, eh, mask, entpart);
  else {
    int b2 = bid - 512;
    gemm64_body(b2 & 31, b2 >> 5, nullptr, ques, emb, W1, 1024, 2048, 64, gpart);
  }
}

__global__ void k_p2(const float* __restrict__ entpart, float* __restrict__ entsum,
                     const float* __restrict__ gpart, const float* __restrict__ b1,
                     float* __restrict__ hbuf) {
  int bid = blockIdx.x;
  if (bid < 4) ent_reduce_body(bid, entpart, entsum);
  else reduce_ep_body(bid - 4, gpart, 16, 64 * 2048, 2048, b1, nullptr, 1, hbuf, nullptr, nullptr);
}

__global__ void k_gemm64(const float* __restrict__ X, const float* __restrict__ W,
                         int K, int N, int KB, float* __restrict__ part) {
  gemm64_body(blockIdx.x, blockIdx.y, X, nullptr, nullptr, W, K, N, KB, part);
}

__global__ void k_reduce_ep(const float* __restrict__ part, int nsplit, int MN, int N,
                            const float* __restrict__ vecB, const float* __restrict__ addend,
                            int mode, float* __restrict__ dst,
                            unsigned short* __restrict__ dhi, unsigned short* __restrict__ dlo) {
  reduce_ep_body(blockIdx.x, part, nsplit, MN, N, vecB, addend, mode, dst, dhi, dlo);
}

// ---------------- big GEMM: logits = Z[64,1024] @ Ws[1024,V] + bs, split-bf16 MFMA -------
// 256 thr = 4 waves; wave w owns cols bx*64 + w*16 .. +15, all 64 rows (4 M-tiles), full K.
// Each Ws element read exactly once per block. Per-lane element offsets (woff) precomputed
// so loads are saddr+voffset with no per-iteration address math; Ws batch double-buffered
// (fc/fn) so the next 8 loads are in flight during convert+MFMA of the current batch.
__global__ __launch_bounds__(256, 4) void k_gemm_big(const unsigned short* __restrict__ zhi,
                                                     const unsigned short* __restrict__ zlo,
                                                     const float* __restrict__ Ws,
                                                     const float* __restrict__ bs,
                                                     float* __restrict__ logits) {
  const int l   = threadIdx.x & 63;
  const int w   = threadIdx.x >> 6;
  const int col = l & 15;
  const int g   = l >> 4;            // k-chunk g*8..g*8+7
  const int c   = blockIdx.x * 64 + w * 16 + col;
  const int cc  = c < V_ ? c : V_ - 1;

  unsigned woff[8];
#pragma unroll
  for (int j = 0; j < 8; ++j) woff[j] = (unsigned)((g * 8 + j) * V_ + cc);

  unsigned aoff[4];
#pragma unroll
  for (int m = 0; m < 4; ++m) aoff[m] = (unsigned)((m * 16 + col) * D_ + g * 8);

  f32x4 zero = {0.f, 0.f, 0.f, 0.f};
  f32x4 acc[4];
#pragma unroll
  for (int m = 0; m < 4; ++m) acc[m] = zero;

  float fc[8], fn[8];
#pragma unroll
  for (int j = 0; j < 8; ++j) fn[j] = 0.f;
#pragma unroll
  for (int j = 0; j < 8; ++j) fc[j] = Ws[woff[j]];

  for (int k0 = 0; k0 < D_; k0 += 32) {
    // prefetch next Ws batch (uniform row base advances; voffsets fixed)
    if (k0 + 32 < D_) {
      const float* wnext = Ws + (size_t)(k0 + 32) * V_;
#pragma unroll
      for (int j = 0; j < 8; ++j) fn[j] = wnext[woff[j]];
    }

    // convert current batch to bf16 hi/lo
    union { bf16x8 v; unsigned u[4]; } bh, bl;
#pragma unroll
    for (int j = 0; j < 4; ++j) {
      unsigned h0 = rne1(fc[2 * j]);
      unsigned h1 = rne1(fc[2 * j + 1]);
      float h0f = __uint_as_float(h0 << 16);
      float h1f = __uint_as_float(h1 << 16);
      bh.u[j] = h0 | (h1 << 16);
      bl.u[j] = rne1(fc[2 * j] - h0f) | (rne1(fc[2 * j + 1] - h1f) << 16);
    }

    const unsigned short* zh = zhi + k0;
    const unsigned short* zl = zlo + k0;
    bf16x8 ah[4], al[4];
#pragma unroll
    for (int m = 0; m < 4; ++m) {
      ah[m] = *(const bf16x8*)(zh + aoff[m]);
      al[m] = *(const bf16x8*)(zl + aoff[m]);
    }

#pragma unroll
    for (int m = 0; m < 4; ++m) acc[m] = __builtin_amdgcn_mfma_f32_16x16x32_bf16(ah[m], bh.v, acc[m], 0, 0, 0);
#pragma unroll
    for (int m = 0; m < 4; ++m) acc[m] = __builtin_amdgcn_mfma_f32_16x16x32_bf16(ah[m], bl.v, acc[m], 0, 0, 0);
#pragma unroll
    for (int m = 0; m < 4; ++m) acc[m] = __builtin_amdgcn_mfma_f32_16x16x32_bf16(al[m], bh.v, acc[m], 0, 0, 0);

#pragma unroll
    for (int j = 0; j < 8; ++j) fc[j] = fn[j];
  }

  if (c < V_) {
    float bias = bs[c];
#pragma unroll
    for (int m = 0; m < 4; ++m) {
#pragma unroll
      for (int i = 0; i < 4; ++i)
        logits[(size_t)(m * 16 + g * 4 + i) * V_ + c] = acc[m][i] + bias;
    }
  }
}

// ---------------- fused softmax: one block per row ----------------
__global__ __launch_bounds__(1024) void k_softmax(const float* __restrict__ logits,
                                                  float* __restrict__ out) {
  __shared__ float sred[16];
  __shared__ float s_mx, s_inv;
  const int tid = threadIdx.x;
  const float* row = logits + (size_t)blockIdx.x * V_;
  float* orow = out + (size_t)blockIdx.x * V_;

  float mx = -3.4e38f;
  for (int i = tid; i < V_; i += 1024) mx = fmaxf(mx, row[i]);
  mx = waveMax(mx);
  if ((tid & 63) == 0) sred[tid >> 6] = mx;
  __syncthreads();
  if (tid == 0) {
    float m = sred[0];
#pragma unroll
    for (int i = 1; i < 16; ++i) m = fmaxf(m, sred[i]);
    s_mx = m;
  }
  __syncthreads();
  const float M = s_mx;

  float s = 0.f;
  for (int i = tid; i < V_; i += 1024) s += __expf(row[i] - M);
  s = waveSum(s);
  if ((tid & 63) == 0) sred[tid >> 6] = s;
  __syncthreads();
  if (tid == 0) {
    float t = 0.f;
#pragma unroll
    for (int i = 0; i < 16; ++i) t += sred[i];
    s_inv = 1.f / t;
  }
  __syncthreads();
  const float inv = s_inv;
  for (int i = tid; i < V_; i += 1024) orow[i] = __expf(row[i] - M) * inv;
}

// ---------------- launch ----------------
extern "C" void kernel_launch(void* const* d_in, const int* in_sizes, int n_in,
                              void* d_out, int out_size, void* d_ws, size_t ws_size,
                              hipStream_t stream) {
  const float* eh   = (const float*)d_in[0];
  const int*   ques = (const int*)d_in[1];
  const void*  mask = d_in[2];
  const float* emb  = (const float*)d_in[3];
  const float* W1   = (const float*)d_in[4];
  const float* b1   = (const float*)d_in[5];
  const float* W2   = (const float*)d_in[6];
  const float* b2   = (const float*)d_in[7];
  const float* A    = (const float*)d_in[8];
  const float* H    = (const float*)d_in[9];
  const float* Ws   = (const float*)d_in[10];
  const float* bs   = (const float*)d_in[11];
  float* out = (float*)d_out;
  char* ws = (char*)d_ws;

  // ws layout (bytes). gpart aliases logits (temporally disjoint).
  float*          logits  = (float*)(ws + 0);           // 64*50257*4 = 12,865,792
  float*          gpart   = (float*)(ws + 0);           // max 8,388,608 (aliased)
  float*          entpart = (float*)(ws + 12866048);    // 2,097,152
  float*          entsum  = (float*)(ws + 14963200);    // 4,096
  float*          hbuf    = (float*)(ws + 14967296);    // 524,288
  float*          qbuf    = (float*)(ws + 15491584);    // 262,144
  float*          ubuf    = (float*)(ws + 15753728);    // 262,144
  unsigned short* zhi16   = (unsigned short*)(ws + 16015872);  // 131,072
  unsigned short* zlo16   = (unsigned short*)(ws + 16146944);  // 131,072

  // P1: ent_partial (512 blocks) || h-gemm partials (512 blocks)
  k_p1<<<1024, 256, 0, stream>>>(eh, mask, entpart, ques, emb, W1, gpart);
  // P2: ent_reduce (4) || h = relu(.+b1) (512)
  k_p2<<<516, 256, 0, stream>>>(entpart, entsum, gpart, b1, hbuf);

  // P3/P4: q = h @ W2 + b2                 [64,1024], K=2048, split 32
  k_gemm64<<<dim3(16, 32), 256, 0, stream>>>(hbuf, W2, 2048, 1024, 64, gpart);
  k_reduce_ep<<<256, 256, 0, stream>>>(gpart, 32, 64 * 1024, 1024, b2, nullptr, 2, qbuf, nullptr, nullptr);

  // P5/P6: u = (q @ A) * ent_sum           [64,1024], split 16
  k_gemm64<<<dim3(16, 16), 256, 0, stream>>>(qbuf, A, 1024, 1024, 64, gpart);
  k_reduce_ep<<<256, 256, 0, stream>>>(gpart, 16, 64 * 1024, 1024, entsum, nullptr, 3, ubuf, nullptr, nullptr);

  // P7/P8: z = q + u @ H (-> bf16 hi/lo)   [64,1024], split 16
  k_gemm64<<<dim3(16, 16), 256, 0, stream>>>(ubuf, H, 1024, 1024, 64, gpart);
  k_reduce_ep<<<256, 256, 0, stream>>>(gpart, 16, 64 * 1024, 1024, nullptr, qbuf, 4, nullptr, zhi16, zlo16);

  // P9: logits = z @ Ws + bs               [64,V], split-bf16 MFMA, deep-pipelined
  k_gemm_big<<<786, 256, 0, stream>>>(zhi16, zlo16, Ws, bs, logits);

  // P10: softmax (one block per row)
  k_softmax<<<64, 1024, 0, stream>>>(logits, out);

  (void)in_sizes; (void)n_in; (void)out_size; (void)ws_size;
}